// Round 9
// baseline (134.017 us; speedup 1.0000x reference)
//
#include <hip/hip_runtime.h>
#include <math.h>

#define T_TOK 16384   // 4*4096 tokens
#define NEXP  64

// Workspace layout (floats):
//   ws[0..63]   : expert load sums
//   ws[64]      : sum of z^2
//   ws[66]      : block-done counter (int)
//   ws[128 ..]  : w_t transposed gate weights [1024][64]
//
// d_out layout (floats, out_size = 65537):
//   [0, 32768)      top-2 renormalized scores [token][2]
//   [32768, 65536)  top-2 expert indices as floats [token][2]
//   [65536]         total_loss

// ---------------------------------------------------------------------------
// prep: tiled transpose gate_w [64][1024] -> w_t [1024][64]; zero accumulators
// ---------------------------------------------------------------------------
__global__ void moe_prep(const float* __restrict__ gw, float* __restrict__ ws) {
    __shared__ float tile[64][65];
    const int b = blockIdx.x;
    const int tid = threadIdx.x;         // 256
    if (b == 0 && tid < 128) ws[tid] = 0.f;
#pragma unroll
    for (int it = 0; it < 16; ++it) {
        int idx = it * 256 + tid;
        int e = idx >> 6, kk = idx & 63;
        tile[e][kk] = gw[e * 1024 + b * 64 + kk];
    }
    __syncthreads();
#pragma unroll
    for (int it = 0; it < 16; ++it) {
        int idx = it * 256 + tid;
        int kk = idx >> 6, e = idx & 63;
        ws[128 + (b * 64 + kk) * 64 + e] = tile[e][kk];
    }
}

// ---------------------------------------------------------------------------
// main: R0-R8 synthesis says the wall is the CU LDS pipe's INSTRUCTION issue
// (~12 cyc/ds_read regardless of width; R0 and R8 both = 512 reads/step =
// identical 53.40 us). This round cuts ds_read count 8x:
//  - lane = token (64 lanes = 64 tokens), waves = 4 e-groups x 4 k-quarters,
//    per-lane tile 1t x 16e (acc[16]).
//  - w operand is WAVE-UNIFORM -> scalar s_load path, SGPR src in v_fma:
//    w leaves the LDS pipe AND the VALU entirely (scalar pipe is free).
//  - x: lane reads its own row, 16 ds_read_b128 per slab, all immediate
//    offsets off one base VGPR. Per CU total: 1024 ds_read (was 8192).
//  - xbuf rows padded to 260 floats (1040 B, odd in 16B quads) -> 64 lane
//    addresses spread over all 8 bank-quads = b128 throughput floor.
//  - staging: proven reg-prefetch (4 f4/thread/slab, K_SLAB=256, 4 slabs,
//    8 barriers). Live ~52 VGPR < 64 hard cap (tripwire: WRITE_SIZE).
// Fold: 4-round kq chain (proven shape); epilogue/losses verbatim.
// ---------------------------------------------------------------------------
__launch_bounds__(1024, 1)
__global__ void moe_main(const float* __restrict__ x,
                         const float* __restrict__ wt,     // [1024][64]
                         float* __restrict__ acc_ws,
                         float* __restrict__ out) {
    __shared__ float xbuf[64 * 260];     // x slab: [t 64][k 256 + 4 pad]
    __shared__ float sc[64 * 68];        // logits, stride 68
    __shared__ float row_inv[64];
    __shared__ float colpart[16][64];
    __shared__ int   is_last;

    const int tid  = threadIdx.x;
    const int lane = tid & 63;           // token within block
    const int wv   = tid >> 6;                                   // 0..15
    const int kq   = __builtin_amdgcn_readfirstlane(wv & 3);     // k quarter
    const int eg   = __builtin_amdgcn_readfirstlane(wv >> 2);    // e 16-group
    const int tok0 = blockIdx.x << 6;

    // ---- staging plan (1024 threads, 4 float4 per slab, coalesced)
    const int rr = tid >> 4;             // 0..63 token row
    const int cg = tid & 15;
    const float* gx = x + (((size_t)(tok0 + rr)) << 10) + (cg << 2);
    float* xw = xbuf + rr * 260 + (cg << 2);

    float acc[16];
#pragma unroll
    for (int j = 0; j < 16; ++j) acc[j] = 0.f;

    // ---- per-lane read base: own token row, own k-quarter (imm offsets)
    const float* xb = xbuf + lane * 260 + (kq << 6);

    // prologue prefetch of slab 0
    float4 px0 = *(const float4*)(gx);
    float4 px1 = *(const float4*)(gx + 64);
    float4 px2 = *(const float4*)(gx + 128);
    float4 px3 = *(const float4*)(gx + 192);

#pragma unroll 1
    for (int s = 0; s < 4; ++s) {
        __syncthreads();                            // buf free
        *(float4*)(xw)       = px0;
        *(float4*)(xw + 64)  = px1;
        *(float4*)(xw + 128) = px2;
        *(float4*)(xw + 192) = px3;
        __syncthreads();                            // buf ready
        if (s < 3) {                                // prefetch next slab
            const int o = (s + 1) << 8;
            px0 = *(const float4*)(gx + o);
            px1 = *(const float4*)(gx + o + 64);
            px2 = *(const float4*)(gx + o + 128);
            px3 = *(const float4*)(gx + o + 192);
        }
        // w base for this wave's 64 k-rows of this slab (wave-uniform)
        const int krow0 = __builtin_amdgcn_readfirstlane((s << 8) + (kq << 6));
        const float* wslab = wt + (krow0 << 6) + (eg << 4);
#pragma unroll
        for (int c = 0; c < 16; ++c) {              // 4 k per chunk
            float4 xv = *(const float4*)(xb + (c << 2));   // 1 ds_read_b128
            float xa[4] = {xv.x, xv.y, xv.z, xv.w};
#pragma unroll
            for (int u = 0; u < 4; ++u) {
                // wave-uniform row -> scalar loads into SGPRs
                const float* wr = wslab + (((c << 2) + u) << 6);
                float4 w0 = *(const float4*)(wr);
                float4 w1 = *(const float4*)(wr + 4);
                float4 w2 = *(const float4*)(wr + 8);
                float4 w3 = *(const float4*)(wr + 12);
                const float xs = xa[u];
                acc[0]  = fmaf(xs, w0.x, acc[0]);
                acc[1]  = fmaf(xs, w0.y, acc[1]);
                acc[2]  = fmaf(xs, w0.z, acc[2]);
                acc[3]  = fmaf(xs, w0.w, acc[3]);
                acc[4]  = fmaf(xs, w1.x, acc[4]);
                acc[5]  = fmaf(xs, w1.y, acc[5]);
                acc[6]  = fmaf(xs, w1.z, acc[6]);
                acc[7]  = fmaf(xs, w1.w, acc[7]);
                acc[8]  = fmaf(xs, w2.x, acc[8]);
                acc[9]  = fmaf(xs, w2.y, acc[9]);
                acc[10] = fmaf(xs, w2.z, acc[10]);
                acc[11] = fmaf(xs, w2.w, acc[11]);
                acc[12] = fmaf(xs, w3.x, acc[12]);
                acc[13] = fmaf(xs, w3.y, acc[13]);
                acc[14] = fmaf(xs, w3.z, acc[14]);
                acc[15] = fmaf(xs, w3.w, acc[15]);
            }
        }
    }

    // ---- fold 4 kq-partials into sc (barrier chain over kq, proven shape)
    float* sp = sc + lane * 68 + (eg << 4);
    if (kq == 0) {
        *(float4*)(sp)      = make_float4(acc[0], acc[1], acc[2], acc[3]);
        *(float4*)(sp + 4)  = make_float4(acc[4], acc[5], acc[6], acc[7]);
        *(float4*)(sp + 8)  = make_float4(acc[8], acc[9], acc[10], acc[11]);
        *(float4*)(sp + 12) = make_float4(acc[12], acc[13], acc[14], acc[15]);
    }
    __syncthreads();
#pragma unroll 1
    for (int r = 1; r < 4; ++r) {
        if (kq == r) {
#pragma unroll
            for (int g = 0; g < 4; ++g) {
                float4 o = *(float4*)(sp + (g << 2));
                o.x += acc[(g << 2)];     o.y += acc[(g << 2) + 1];
                o.z += acc[(g << 2) + 2]; o.w += acc[(g << 2) + 3];
                *(float4*)(sp + (g << 2)) = o;
            }
        }
        __syncthreads();
    }

    // ---- per-token epilogue (serial, proven absmax 0)
    if (tid < 64) {
        const int r = tid;
        const float* srow = sc + r * 68;
        float v1 = -1e30f, v2 = -1e30f;
        int i1 = 0, i2 = 0;
        for (int j = 0; j < 64; ++j) {
            float l = srow[j];
            if (l > v1)      { v2 = v1; i2 = i1; v1 = l; i1 = j; }
            else if (l > v2) { v2 = l; i2 = j; }
        }
        float m = v1;
        float ssum = 0.f;
        for (int j = 0; j < 64; ++j) {
            float ev = expf(srow[j] - m);
            ssum += ev;
            sc[r * 68 + j] = ev;
        }
        float inv = 1.f / ssum;
        row_inv[r] = inv;
        float z = m + logf(ssum);
        float zsq = z * z;
#pragma unroll
        for (int off = 32; off > 0; off >>= 1) zsq += __shfl_down(zsq, off);
        if (lane == 0) atomicAdd(acc_ws + 64, zsq);

        float p1s = inv;                        // exp(v1-m) == 1
        float p2s = expf(v2 - m) * inv;
        float bb  = expf(p2s - p1s);
        float s1 = 1.f / (1.f + bb);
        float s2 = bb * s1;
        int t = tok0 + r;
        out[2 * t]     = s1;
        out[2 * t + 1] = s2;
        out[2 * T_TOK + 2 * t]     = (float)i1;
        out[2 * T_TOK + 2 * t + 1] = (float)i2;
    }
    __syncthreads();

    // ---- expert load column sums (16 row-groups of 4 rows)
    {
        int e  = tid & 63;
        int rg = tid >> 6;                      // 0..15
        float sum = 0.f;
#pragma unroll
        for (int r2 = 0; r2 < 4; ++r2) {
            int row = (rg << 2) + r2;
            sum += sc[row * 68 + e] * row_inv[row];
        }
        colpart[rg][e] = sum;
    }
    __syncthreads();
    if (tid < 64) {
        float tot = 0.f;
#pragma unroll
        for (int rg = 0; rg < 16; ++rg) tot += colpart[rg][tid];
        atomicAdd(acc_ws + tid, tot);           // device-scope
    }

    // ---- last-block finalize
    __syncthreads();
    if (tid == 0) {
        __threadfence();
        int old = __hip_atomic_fetch_add((int*)(acc_ws + 66), 1,
                                         __ATOMIC_ACQ_REL, __HIP_MEMORY_SCOPE_AGENT);
        is_last = (old == 255) ? 1 : 0;
    }
    __syncthreads();
    if (is_last && tid < 64) {
        __threadfence();
        float load = __hip_atomic_load(acc_ws + tid, __ATOMIC_RELAXED,
                                       __HIP_MEMORY_SCOPE_AGENT) * (1.f / 16384.f);
        float d = load - (1.f / 64.f);
        float v = d * d;
#pragma unroll
        for (int off = 32; off > 0; off >>= 1) v += __shfl_down(v, off);
        if (tid == 0) {
            float zsum = __hip_atomic_load(acc_ws + 64, __ATOMIC_RELAXED,
                                           __HIP_MEMORY_SCOPE_AGENT);
            float lb = 0.01f * 64.f * v;
            float zl = 1e-4f * zsum * (1.f / 16384.f);
            out[4 * T_TOK] = lb + zl;
        }
    }
}

extern "C" void kernel_launch(void* const* d_in, const int* in_sizes, int n_in,
                              void* d_out, int out_size, void* d_ws, size_t ws_size,
                              hipStream_t stream) {
    const float* x  = (const float*)d_in[0];   // [4,4096,1024] fp32
    const float* gw = (const float*)d_in[1];   // [64,1024] fp32
    float* out = (float*)d_out;                // 65537 fp32
    float* ws  = (float*)d_ws;

    moe_prep<<<16, 256, 0, stream>>>(gw, ws);
    moe_main<<<256, 1024, 0, stream>>>(x, ws + 128, ws, out);
}

// Round 10
// 128.463 us; speedup vs baseline: 1.0432x; 1.0432x over previous
//
#include <hip/hip_runtime.h>
#include <math.h>

#define T_TOK 16384   // 4*4096 tokens
#define NEXP  64

// Workspace layout (floats):
//   ws[0..63]   : expert load sums
//   ws[64]      : sum of z^2
//   ws[66]      : block-done counter (int)
//   ws[128 ..]  : w_t transposed gate weights [1024][64]
//
// d_out layout (floats, out_size = 65537):
//   [0, 32768)      top-2 renormalized scores [token][2]
//   [32768, 65536)  top-2 expert indices as floats [token][2]
//   [65536]         total_loss

// ---------------------------------------------------------------------------
// prep: tiled transpose gate_w [64][1024] -> w_t [1024][64]; zero accumulators
// ---------------------------------------------------------------------------
__global__ void moe_prep(const float* __restrict__ gw, float* __restrict__ ws) {
    __shared__ float tile[64][65];
    const int b = blockIdx.x;
    const int tid = threadIdx.x;         // 256
    if (b == 0 && tid < 128) ws[tid] = 0.f;
#pragma unroll
    for (int it = 0; it < 16; ++it) {
        int idx = it * 256 + tid;
        int e = idx >> 6, kk = idx & 63;
        tile[e][kk] = gw[e * 1024 + b * 64 + kk];
    }
    __syncthreads();
#pragma unroll
    for (int it = 0; it < 16; ++it) {
        int idx = it * 256 + tid;
        int kk = idx >> 6, e = idx & 63;
        ws[128 + (b * 64 + kk) * 64 + e] = tile[e][kk];
    }
}

// ---------------------------------------------------------------------------
// fold helpers: store/add a lane's 8t x 8e partial (rows ta+8i, interleaved)
// into a stride-68 buffer. Write fan: addr dword = (ta+8i)*68 + eb*8 ==
// 4*ta + 8*eb (mod 32) -> 64 lanes spread over all 8 bank-quads, balanced.
// All acc indices compile-time (full unroll).
// ---------------------------------------------------------------------------
__device__ __forceinline__ void pst88(float* B, const float (&a)[8][8],
                                      int ta, int eb) {
#pragma unroll
    for (int i = 0; i < 8; ++i) {
        float* p = B + (ta + (i << 3)) * 68 + (eb << 3);
        *(float4*)(p)     = make_float4(a[i][0], a[i][1], a[i][2], a[i][3]);
        *(float4*)(p + 4) = make_float4(a[i][4], a[i][5], a[i][6], a[i][7]);
    }
}
__device__ __forceinline__ void pad88(float* B, const float (&a)[8][8],
                                      int ta, int eb) {
#pragma unroll
    for (int i = 0; i < 8; ++i) {
        float* p = B + (ta + (i << 3)) * 68 + (eb << 3);
        float4 v0 = *(float4*)(p);
        float4 v1 = *(float4*)(p + 4);
        v0.x += a[i][0]; v0.y += a[i][1]; v0.z += a[i][2]; v0.w += a[i][3];
        v1.x += a[i][4]; v1.y += a[i][5]; v1.z += a[i][6]; v1.w += a[i][7];
        *(float4*)(p)     = v0;
        *(float4*)(p + 4) = v1;
    }
}

// ---------------------------------------------------------------------------
// main: 8t x 8e per-lane tile -- 1:16 ds_read:FMA (R0 was 1:8), bank-audited.
// R0-R9 synthesis: wall = LDS pipe instruction/phase throughput (~12 cyc per
// well-spread b128; 4x worse when the distinct lane addresses alias one
// bank-quad, which is what sank R1). Requires acc[64] -> >64 VGPR, so:
// 512 threads + __launch_bounds__(512,1) = 8 waves/CU -> VGPR cap 256
// ((1024,*) pins 64 in this toolchain; (512,4) pinned 64 = 32 waves/CU).
// Block 64t x 64e; 8 waves = 8-way k-split (wave wv: k = s*64+wv*8+[0,8)).
// Tokens INTERLEAVED per lane: t = ta + 8i, xbuf stride 68 -> x-read fan
// ta*68 == ta*4 (mod 32): 8 distinct bank-quads, conflict-free; eb lanes
// broadcast. w slab stride 68, read k*68 + eb*8: 64 consecutive dwords,
// balanced. Staging: proven 2-barrier step + reg prefetch (4 f4).
// Fold: R8's 2-chain + merge; epilogue/losses verbatim (absmax-0 lineage).
// Tripwires: VGPR_Count >64 expected (else cap is universal); WRITE ~336 KB.
// ---------------------------------------------------------------------------
__launch_bounds__(512, 1)
__global__ void moe_main(const float* __restrict__ x,
                         const float* __restrict__ wt,     // [1024][64]
                         float* __restrict__ acc_ws,
                         float* __restrict__ out) {
    __shared__ float xbuf[64 * 68];      // x slab [t 64][k 64], stride 68
    __shared__ float wbuf[64 * 68];      // w slab [k 64][e 64], stride 68
    __shared__ float sc[64 * 68];        // logits, stride 68
    __shared__ float fb[64 * 68];        // fold scratch, stride 68
    __shared__ float row_inv[64];
    __shared__ float colpart[8][64];
    __shared__ int   is_last;

    const int tid  = threadIdx.x;
    const int lane = tid & 63;
    const int wv   = __builtin_amdgcn_readfirstlane(tid >> 6);   // 0..7 k-octet
    const int ta   = lane >> 3;          // token sub-row: t = ta + 8i
    const int eb   = lane & 7;           // expert octet: e = eb*8 + j
    const int tok0 = blockIdx.x << 6;

    // ---- staging plan (512 threads, 2 f4 x + 2 f4 w per step, coalesced)
    const int rr  = tid >> 3;            // 0..63 (x: token row / w: k row)
    const int sub = tid & 7;             // chunk low (stages sub and sub+8)
    const float* gx = x + (((size_t)(tok0 + rr)) << 10) + (sub << 2);
    const float* gw = wt + (rr << 6) + (sub << 2);
    const int slo = rr * 68 + (sub << 2);     // same layout both slabs

    float acc[8][8];
#pragma unroll
    for (int i = 0; i < 8; ++i)
#pragma unroll
        for (int j = 0; j < 8; ++j) acc[i][j] = 0.f;

    // prologue prefetch of step 0
    float4 px0 = *(const float4*)(gx);
    float4 px1 = *(const float4*)(gx + 32);
    float4 pw0 = *(const float4*)(gw);
    float4 pw1 = *(const float4*)(gw + 32);

#pragma unroll 1
    for (int s = 0; s < 16; ++s) {
        __syncthreads();                            // bufs free
        *(float4*)(xbuf + slo)      = px0;
        *(float4*)(xbuf + slo + 32) = px1;
        *(float4*)(wbuf + slo)      = pw0;
        *(float4*)(wbuf + slo + 32) = pw1;
        __syncthreads();                            // bufs ready
        if (s < 15) {                               // prefetch next step
            px0 = *(const float4*)(gx + ((s + 1) << 6));
            px1 = *(const float4*)(gx + ((s + 1) << 6) + 32);
            pw0 = *(const float4*)(gw + ((s + 1) << 12));
            pw1 = *(const float4*)(gw + ((s + 1) << 12) + 32);
        }
#pragma unroll
        for (int cc = 0; cc < 2; ++cc) {
            const int c4 = (wv << 3) + (cc << 2);   // k-chunk float offset
            float xr[8][4];
#pragma unroll
            for (int i = 0; i < 8; ++i) {
                float4 v = *(const float4*)(xbuf + (ta + (i << 3)) * 68 + c4);
                xr[i][0] = v.x; xr[i][1] = v.y; xr[i][2] = v.z; xr[i][3] = v.w;
            }
#pragma unroll
            for (int u = 0; u < 4; ++u) {
                const float* wr = wbuf + (c4 + u) * 68 + (eb << 3);
                float4 w0 = *(const float4*)(wr);
                float4 w1 = *(const float4*)(wr + 4);
                float wa[8] = {w0.x, w0.y, w0.z, w0.w,
                               w1.x, w1.y, w1.z, w1.w};
#pragma unroll
                for (int i = 0; i < 8; ++i) {
                    const float xs = xr[i][u];
#pragma unroll
                    for (int j = 0; j < 8; ++j)
                        acc[i][j] = fmaf(xs, wa[j], acc[i][j]);
                }
            }
        }
    }

    // ---- fold 8 k-octet partials via 2 chains + merge (R8-proven shape)
    if      (wv == 0) pst88(sc, acc, ta, eb);
    else if (wv == 1) pst88(fb, acc, ta, eb);
    __syncthreads();
    if      (wv == 2) pad88(sc, acc, ta, eb);
    else if (wv == 3) pad88(fb, acc, ta, eb);
    __syncthreads();
    if      (wv == 4) pad88(sc, acc, ta, eb);
    else if (wv == 5) pad88(fb, acc, ta, eb);
    __syncthreads();
    if      (wv == 6) pad88(sc, acc, ta, eb);
    else if (wv == 7) pad88(fb, acc, ta, eb);
    __syncthreads();
    {   // sc += fb (512 threads; 64 rows x 16 granules, 2 f4 each)
        const int row = tid >> 3, g = tid & 7;
        float* ps = sc + row * 68 + (g << 2);
        const float* pf = fb + row * 68 + (g << 2);
        float4 a0 = *(float4*)(ps);
        float4 b0 = *(const float4*)(pf);
        a0.x += b0.x; a0.y += b0.y; a0.z += b0.z; a0.w += b0.w;
        *(float4*)(ps) = a0;
        float4 a1 = *(float4*)(ps + 32);
        float4 b1 = *(const float4*)(pf + 32);
        a1.x += b1.x; a1.y += b1.y; a1.z += b1.z; a1.w += b1.w;
        *(float4*)(ps + 32) = a1;
    }
    __syncthreads();

    // ---- per-token epilogue (serial, proven absmax 0)
    if (tid < 64) {
        const int r = tid;
        const float* srow = sc + r * 68;
        float v1 = -1e30f, v2 = -1e30f;
        int i1 = 0, i2 = 0;
        for (int j = 0; j < 64; ++j) {
            float l = srow[j];
            if (l > v1)      { v2 = v1; i2 = i1; v1 = l; i1 = j; }
            else if (l > v2) { v2 = l; i2 = j; }
        }
        float m = v1;
        float ssum = 0.f;
        for (int j = 0; j < 64; ++j) {
            float ev = expf(srow[j] - m);
            ssum += ev;
            sc[r * 68 + j] = ev;
        }
        float inv = 1.f / ssum;
        row_inv[r] = inv;
        float z = m + logf(ssum);
        float zsq = z * z;
#pragma unroll
        for (int off = 32; off > 0; off >>= 1) zsq += __shfl_down(zsq, off);
        if (lane == 0) atomicAdd(acc_ws + 64, zsq);

        float p1s = inv;                        // exp(v1-m) == 1
        float p2s = expf(v2 - m) * inv;
        float bb  = expf(p2s - p1s);
        float s1 = 1.f / (1.f + bb);
        float s2 = bb * s1;
        int t = tok0 + r;
        out[2 * t]     = s1;
        out[2 * t + 1] = s2;
        out[2 * T_TOK + 2 * t]     = (float)i1;
        out[2 * T_TOK + 2 * t + 1] = (float)i2;
    }
    __syncthreads();

    // ---- expert load column sums (8 row-groups of 8 rows)
    {
        int e  = tid & 63;
        int rg = tid >> 6;                      // 0..7
        float sum = 0.f;
#pragma unroll
        for (int r2 = 0; r2 < 8; ++r2) {
            int row = (rg << 3) + r2;
            sum += sc[row * 68 + e] * row_inv[row];
        }
        colpart[rg][e] = sum;
    }
    __syncthreads();
    if (tid < 64) {
        float tot = 0.f;
#pragma unroll
        for (int rg = 0; rg < 8; ++rg) tot += colpart[rg][tid];
        atomicAdd(acc_ws + tid, tot);           // device-scope
    }

    // ---- last-block finalize
    __syncthreads();
    if (tid == 0) {
        __threadfence();
        int old = __hip_atomic_fetch_add((int*)(acc_ws + 66), 1,
                                         __ATOMIC_ACQ_REL, __HIP_MEMORY_SCOPE_AGENT);
        is_last = (old == 255) ? 1 : 0;
    }
    __syncthreads();
    if (is_last && tid < 64) {
        __threadfence();
        float load = __hip_atomic_load(acc_ws + tid, __ATOMIC_RELAXED,
                                       __HIP_MEMORY_SCOPE_AGENT) * (1.f / 16384.f);
        float d = load - (1.f / 64.f);
        float v = d * d;
#pragma unroll
        for (int off = 32; off > 0; off >>= 1) v += __shfl_down(v, off);
        if (tid == 0) {
            float zsum = __hip_atomic_load(acc_ws + 64, __ATOMIC_RELAXED,
                                           __HIP_MEMORY_SCOPE_AGENT);
            float lb = 0.01f * 64.f * v;
            float zl = 1e-4f * zsum * (1.f / 16384.f);
            out[4 * T_TOK] = lb + zl;
        }
    }
}

extern "C" void kernel_launch(void* const* d_in, const int* in_sizes, int n_in,
                              void* d_out, int out_size, void* d_ws, size_t ws_size,
                              hipStream_t stream) {
    const float* x  = (const float*)d_in[0];   // [4,4096,1024] fp32
    const float* gw = (const float*)d_in[1];   // [64,1024] fp32
    float* out = (float*)d_out;                // 65537 fp32
    float* ws  = (float*)d_ws;

    moe_prep<<<16, 256, 0, stream>>>(gw, ws);
    moe_main<<<256, 512, 0, stream>>>(x, ws + 128, ws, out);
}